// Round 14
// baseline (620.148 us; speedup 1.0000x reference)
//
#include <hip/hip_runtime.h>
#include <hip/hip_bf16.h>

// PointTransformerBlock, round 14: register-chain edge kernel (r5 resurrected)
// with lmap-ordered global activation storage.
//   r5 (register-resident swapped-MFMA, PASSED correctness) was slow only due
//   to scattered 8B gathers (FETCH 1.36GB). Fix: a_src/a_dst/v stored so that
//   position p holds semantic channel lmap(p) -> each lane's B-frag chunk is
//   one contiguous 16B load; per edge-row the 4 g-lanes x 2 kk cover the full
//   128B row as 64B segments. Edge kernel: ZERO LDS activation traffic, zero
//   fences, one LN reduce per group. Gathers issued at group top (T14 cover).
//   lmap(q) = 32*(q>>5) + 16*((q&7)>>2) + 4*((q>>3)&3) + (q&3)
//   inv(c)  = 32*(c>>5) + 8*((c>>2)&3) + 4*((c>>4)&1) + (c&3)

typedef __bf16 bf16x8 __attribute__((ext_vector_type(8)));
typedef short  s16x8  __attribute__((ext_vector_type(8)));
typedef float  f32x4  __attribute__((ext_vector_type(4)));

union B8 { s16x8 v; unsigned int u[4]; };

#define SWZ(b) ((b) ^ ((((b) >> 7) & 7) << 4))

__device__ __forceinline__ unsigned short f2b(float f) {
  union { __hip_bfloat16 h; unsigned short u; } c;
  c.h = __float2bfloat16(f);
  return c.u;
}
__device__ __forceinline__ unsigned int pack2(float a, float b) {
  return (unsigned int)f2b(a) | ((unsigned int)f2b(b) << 16);
}
__device__ __forceinline__ void unpack2(unsigned int u, float& a, float& b) {
  union { unsigned int x; float f; } t0, t1;
  t0.x = u << 16; t1.x = u & 0xffff0000u;
  a = t0.f; b = t1.f;
}
__device__ __forceinline__ void unpack8(uint4 u, float* v) {
  unpack2(u.x, v[0], v[1]); unpack2(u.y, v[2], v[3]);
  unpack2(u.z, v[4], v[5]); unpack2(u.w, v[6], v[7]);
}

template <int CTRL>
__device__ __forceinline__ float dppf(float x) {
  return __builtin_bit_cast(float,
      __builtin_amdgcn_update_dpp(0, __builtin_bit_cast(int, x), CTRL, 0xF, 0xF, false));
}
template <int CTRL>
__device__ __forceinline__ int dppi(int x, int old) {
  return __builtin_amdgcn_update_dpp(old, x, CTRL, 0xF, 0xF, false);
}

// k-position q of B-frag holds semantic channel lmap(q)
__device__ __forceinline__ int lmap(int q) {
  int kk = q >> 5, gg = (q >> 3) & 3, j = q & 7;
  return 32 * kk + 16 * (j >> 2) + 4 * gg + (j & 3);
}

// plain staging: W[k][c] -> W^T [c][k] bf16, swizzled
__device__ __forceinline__ void stage_wt(const float* __restrict__ W, char* dst, int tid) {
  for (int idx = tid; idx < 2048; idx += 256) {
    int c  = idx >> 5;
    int k2 = (idx & 31) << 1;
    *(unsigned int*)(dst + SWZ(c * 128 + k2 * 2)) = pack2(W[k2 * 64 + c], W[(k2 + 1) * 64 + c]);
  }
}
// k-rows permuted: position k holds W[lmap(k)][c]
__device__ __forceinline__ void stage_wt_perm(const float* __restrict__ W, char* dst, int tid) {
  for (int idx = tid; idx < 2048; idx += 256) {
    int c  = idx >> 5;
    int k2 = (idx & 31) << 1;
    *(unsigned int*)(dst + SWZ(c * 128 + k2 * 2)) =
        pack2(W[lmap(k2) * 64 + c], W[lmap(k2 + 1) * 64 + c]);
  }
}

// act-major 16-row GEMM used by node/out kernels (A=act rows from LDS)
__device__ __forceinline__ void gemm16(const char* actb, const char* wb,
                                       int g, int m, f32x4 acc[4]) {
  #pragma unroll
  for (int kk = 0; kk < 2; kk++) {
    s16x8 af = *(const s16x8*)(actb + SWZ(m * 128 + g * 16 + kk * 64));
    #pragma unroll
    for (int t = 0; t < 4; t++) {
      s16x8 bf = *(const s16x8*)(wb + SWZ((t * 16 + m) * 128 + g * 16 + kk * 64));
      acc[t] = __builtin_amdgcn_mfma_f32_16x16x32_bf16(
          __builtin_bit_cast(bf16x8, af), __builtin_bit_cast(bf16x8, bf), acc[t], 0, 0, 0);
    }
  }
}

// ---------------- node linears (MFMA), bf16 outputs in inv-lmap order -------
__global__ __launch_bounds__(256, 3) void node_mfma_kernel(
    const float* __restrict__ x,
    const float* __restrict__ W_in, const float* __restrict__ b_in,
    const float* __restrict__ W_lin, const float* __restrict__ W_src, const float* __restrict__ W_dst,
    unsigned short* __restrict__ a_srcB, unsigned short* __restrict__ a_dstB,
    unsigned short* __restrict__ vB, int N)
{
  __shared__ __align__(16) char sWinT[8192], sWsT[8192], sWdT[8192], sWlT[8192], sX[8192];
  __shared__ __align__(16) float sB[64];
  int tid = threadIdx.x;
  stage_wt(W_in,  sWinT, tid);
  stage_wt(W_src, sWsT,  tid);
  stage_wt(W_dst, sWdT,  tid);
  stage_wt(W_lin, sWlT,  tid);
  if (tid < 64) sB[tid] = b_in[tid];

  const int lane = tid & 63, wv = tid >> 6;
  const int g = lane >> 4, m = lane & 15;
  const int ew = wv << 4;
  const int srow = tid >> 2, sc0 = (tid & 3) << 4;
  const int ntile = (N + 63) >> 6;

  // store position for channel c = 16t+m:  p = 32*(t>>1)+8*(m>>2)+4*(t&1)+(m&3)
  int pstore[4];
  #pragma unroll
  for (int t = 0; t < 4; t++)
    pstore[t] = 32 * (t >> 1) + 8 * (m >> 2) + 4 * (t & 1) + (m & 3);

  for (int tile = blockIdx.x; tile < ntile; tile += gridDim.x) {
    const int rbase = tile << 6;
    __syncthreads();
    {
      int gr = rbase + srow; if (gr >= N) gr = N - 1;
      const float4* src = (const float4*)&x[(size_t)gr * 64 + sc0];
      #pragma unroll
      for (int q = 0; q < 4; q++) {
        float4 f = src[q];
        int byte = srow * 128 + sc0 * 2 + q * 8;
        *(unsigned int*)(sX + SWZ(byte))     = pack2(f.x, f.y);
        *(unsigned int*)(sX + SWZ(byte + 4)) = pack2(f.z, f.w);
      }
    }
    __syncthreads();

    f32x4 a0[4] = {};
    gemm16(sX + ew * 128, sWinT, g, m, a0);
    float x1[4][4];
    #pragma unroll
    for (int t = 0; t < 4; t++)
      #pragma unroll
      for (int r = 0; r < 4; r++) x1[t][r] = fmaxf(a0[t][r] + sB[t * 16 + m], 0.f);
    __syncthreads();
    #pragma unroll
    for (int t = 0; t < 4; t++)
      #pragma unroll
      for (int r = 0; r < 4; r++)
        *(unsigned short*)(sX + SWZ((ew + 4 * g + r) * 128 + (t * 16 + m) * 2)) = f2b(x1[t][r]);
    __syncthreads();

    f32x4 as[4] = {}, ad[4] = {}, al[4] = {};
    gemm16(sX + ew * 128, sWsT, g, m, as);
    gemm16(sX + ew * 128, sWdT, g, m, ad);
    gemm16(sX + ew * 128, sWlT, g, m, al);
    #pragma unroll
    for (int t = 0; t < 4; t++)
      #pragma unroll
      for (int r = 0; r < 4; r++) {
        int gr = rbase + ew + 4 * g + r;
        if (gr < N) {
          size_t o = (size_t)gr * 64 + pstore[t];
          a_srcB[o] = f2b(as[t][r]); a_dstB[o] = f2b(ad[t][r]); vB[o] = f2b(al[t][r]);
        }
      }
  }
}

// ---------------- CSR build ----------------
__global__ void hist_kernel(const int* __restrict__ ei, int* __restrict__ deg, int E, int Etot) {
  int stride = gridDim.x * blockDim.x;
  for (int e = blockIdx.x * blockDim.x + threadIdx.x; e < Etot; e += stride) {
    int d = (e < E) ? ei[E + e] : (e - E);
    atomicAdd(&deg[d], 1);
  }
}

__global__ __launch_bounds__(256) void scanA_kernel(const int* __restrict__ deg, int* __restrict__ chunkSum, int N) {
  __shared__ int s[256];
  int i = blockIdx.x * 256 + threadIdx.x;
  s[threadIdx.x] = (i < N) ? deg[i] : 0;
  __syncthreads();
  for (int off = 128; off > 0; off >>= 1) {
    if (threadIdx.x < off) s[threadIdx.x] += s[threadIdx.x + off];
    __syncthreads();
  }
  if (threadIdx.x == 0) chunkSum[blockIdx.x] = s[0];
}

__global__ __launch_bounds__(256) void scanB_kernel(const int* __restrict__ chunkSum, int* __restrict__ chunkPre, int nchunk) {
  __shared__ int s[256];
  int t = threadIdx.x;
  int v = (t < nchunk) ? chunkSum[t] : 0;
  s[t] = v; __syncthreads();
  for (int off = 1; off < 256; off <<= 1) {
    int x = (t >= off) ? s[t - off] : 0;
    __syncthreads();
    s[t] += x;
    __syncthreads();
  }
  if (t < nchunk) chunkPre[t] = s[t] - v;
}

__global__ __launch_bounds__(256) void scanC_kernel(const int* __restrict__ deg, const int* __restrict__ chunkPre,
                                                    int* __restrict__ cursor, int N) {
  __shared__ int s[256];
  int t = threadIdx.x;
  int i = blockIdx.x * 256 + t;
  int v = (i < N) ? deg[i] : 0;
  s[t] = v; __syncthreads();
  for (int off = 1; off < 256; off <<= 1) {
    int x = (t >= off) ? s[t - off] : 0;
    __syncthreads();
    s[t] += x;
    __syncthreads();
  }
  if (i < N) cursor[i] = chunkPre[blockIdx.x] + s[t] - v;
}

__global__ void scatter_kernel(const int* __restrict__ ei, int* __restrict__ cursor,
                               const float* __restrict__ pos,
                               int* __restrict__ srcS, int* __restrict__ dstS,
                               float4* __restrict__ pd4,
                               int E, int Etot) {
  int stride = gridDim.x * blockDim.x;
  for (int e = blockIdx.x * blockDim.x + threadIdx.x; e < Etot; e += stride) {
    int s, d;
    if (e < E) { s = ei[e]; d = ei[E + e]; }
    else       { s = e - E; d = s; }
    int p = atomicAdd(&cursor[d], 1);
    srcS[p] = s; dstS[p] = d;
    float4 q;
    q.x = pos[d * 3 + 0] - pos[s * 3 + 0];
    q.y = pos[d * 3 + 1] - pos[s * 3 + 1];
    q.z = pos[d * 3 + 2] - pos[s * 3 + 2];
    q.w = 0.f;
    pd4[p] = q;
  }
}

// ---------------- register-chain fused edge kernel ----------------
__global__ __launch_bounds__(256, 2) void edge_kernel(
    const int* __restrict__ srcS, const int* __restrict__ dstS, const float4* __restrict__ pd4,
    const unsigned short* __restrict__ a_srcB, const unsigned short* __restrict__ a_dstB,
    const unsigned short* __restrict__ vBg,
    const float* __restrict__ pos_W1, const float* __restrict__ pos_b1,
    const float* __restrict__ pos_gg, const float* __restrict__ pos_beta,
    const float* __restrict__ pos_W2, const float* __restrict__ pos_b2,
    const float* __restrict__ att_W1, const float* __restrict__ att_b1,
    const float* __restrict__ att_gg, const float* __restrict__ att_beta,
    const float* __restrict__ att_W2, const float* __restrict__ att_b2,
    float* __restrict__ numer, float* __restrict__ denom,
    int G, int gpw)
{
  __shared__ __align__(16) char sW2t[8192], sA1t[8192], sA2t[8192];
  __shared__ __align__(16) float sPW1[192];
  __shared__ __align__(16) float sPB1[64], sPG[64], sPBeta[64], sPB2[64];
  __shared__ __align__(16) float sAB1[64], sAG[64], sABeta[64], sAB2[64];

  int tid = threadIdx.x;
  stage_wt(pos_W2, sW2t, tid);        // k = pos-hidden positions, identity
  stage_wt_perm(att_W1, sA1t, tid);   // k = real channel, lmap-permuted
  stage_wt_perm(att_W2, sA2t, tid);   // k = att-hidden,  lmap-permuted
  for (int i = tid; i < 192; i += 256) sPW1[i] = pos_W1[i];
  if (tid < 64) {
    sPB1[tid] = pos_b1[tid]; sPG[tid] = pos_gg[tid]; sPBeta[tid] = pos_beta[tid]; sPB2[tid] = pos_b2[tid];
    sAB1[tid] = att_b1[tid]; sAG[tid] = att_gg[tid]; sABeta[tid] = att_beta[tid]; sAB2[tid] = att_b2[tid];
  }
  __syncthreads();  // only barrier in kernel

  const int lane = tid & 63;
  const int g = lane >> 4, m = lane & 15;

  const int w  = blockIdx.x * 4 + (tid >> 6);
  const int g0 = w * gpw;
  int g1 = g0 + gpw; if (g1 > G) g1 = G;

  for (int grp = g0; grp < g1; ++grp) {
    const int ebase = grp << 4;

    // ---- meta: lane owns edge m (all 4 g-rows share it) ----
    int d  = dstS[ebase + m];
    int sN = srcS[ebase + m];
    const bool valid = d >= 0;
    const int dm = valid ? d : 0;
    f32x4 pd = *(const f32x4*)&pd4[ebase + m];

    // ---- issue all gathers NOW (16B contiguous; consumed 1-3 GEMMs later) ----
    uint4 AD[2], AS[2], VV[2];
    #pragma unroll
    for (int kk = 0; kk < 2; kk++) {
      size_t off = (size_t)(8 * g + 32 * kk);
      AD[kk] = *(const uint4*)&a_dstB[(size_t)dm * 64 + off];
      AS[kk] = *(const uint4*)&a_srcB[(size_t)sN * 64 + off];
      VV[kk] = *(const uint4*)&vBg[(size_t)sN * 64 + off];
    }

    // ---- Phase A: h = relu(LN(pd @ posW1 + b1)), lane ch q=8g+32kk+j ----
    float u[2][8];
    #pragma unroll
    for (int kk = 0; kk < 2; kk++)
      #pragma unroll
      for (int h = 0; h < 2; h++) {
        int q = 8 * g + 32 * kk + 4 * h;
        f32x4 w0 = *(const f32x4*)&sPW1[q];
        f32x4 w1 = *(const f32x4*)&sPW1[64 + q];
        f32x4 w2 = *(const f32x4*)&sPW1[128 + q];
        f32x4 bb = *(const f32x4*)&sPB1[q];
        #pragma unroll
        for (int r = 0; r < 4; r++)
          u[kk][4 * h + r] = fmaf(pd[0], w0[r], fmaf(pd[1], w1[r], fmaf(pd[2], w2[r], bb[r])));
      }
    {
      float s1 = 0.f;
      #pragma unroll
      for (int kk = 0; kk < 2; kk++)
        #pragma unroll
        for (int j = 0; j < 8; j++) s1 += u[kk][j];
      s1 += __shfl_xor(s1, 16); s1 += __shfl_xor(s1, 32);
      float mean = s1 * (1.f / 64.f);
      float qv = 0.f;
      #pragma unroll
      for (int kk = 0; kk < 2; kk++)
        #pragma unroll
        for (int j = 0; j < 8; j++) { float dd = u[kk][j] - mean; qv = fmaf(dd, dd, qv); }
      qv += __shfl_xor(qv, 16); qv += __shfl_xor(qv, 32);
      float rs = rsqrtf(qv * (1.f / 64.f) + 1e-5f);
      #pragma unroll
      for (int kk = 0; kk < 2; kk++)
        #pragma unroll
        for (int h = 0; h < 2; h++) {
          int q = 8 * g + 32 * kk + 4 * h;
          f32x4 gg4 = *(const f32x4*)&sPG[q];
          f32x4 bt4 = *(const f32x4*)&sPBeta[q];
          #pragma unroll
          for (int r = 0; r < 4; r++)
            u[kk][4 * h + r] = fmaxf(fmaf((u[kk][4 * h + r] - mean) * rs, gg4[r], bt4[r]), 0.f);
        }
    }
    B8 bA[2];
    #pragma unroll
    for (int kk = 0; kk < 2; kk++)
      #pragma unroll
      for (int p = 0; p < 4; p++)
        bA[kk].u[p] = pack2(u[kk][2 * p], u[kk][2 * p + 1]);

    // ---- GEMM1: delta = posW2^T @ h  (lane -> ch 16t+4g+r of edge m) ----
    f32x4 del[4] = {};
    #pragma unroll
    for (int kk = 0; kk < 2; kk++)
      #pragma unroll
      for (int t = 0; t < 4; t++) {
        s16x8 wf = *(const s16x8*)(sW2t + SWZ((t * 16 + m) * 128 + g * 16 + kk * 64));
        del[t] = __builtin_amdgcn_mfma_f32_16x16x32_bf16(
            __builtin_bit_cast(bf16x8, wf), __builtin_bit_cast(bf16x8, bA[kk].v), del[t], 0, 0, 0);
      }
    #pragma unroll
    for (int t = 0; t < 4; t++) {
      f32x4 b2 = *(const f32x4*)&sPB2[16 * t + 4 * g];
      #pragma unroll
      for (int r = 0; r < 4; r++) del[t][r] += b2[r];
    }

    // ---- attin = a_dst - a_src + delta, packed to B-frag (lmap aligned) ----
    B8 bT[2];
    #pragma unroll
    for (int kk = 0; kk < 2; kk++) {
      float da[8], sa[8];
      unpack8(AD[kk], da); unpack8(AS[kk], sa);
      float e[8];
      #pragma unroll
      for (int j = 0; j < 8; j++)
        e[j] = da[j] - sa[j] + del[2 * kk + (j >> 2)][j & 3];
      #pragma unroll
      for (int p = 0; p < 4; p++)
        bT[kk].u[p] = pack2(e[2 * p], e[2 * p + 1]);
    }

    // ---- GEMM2 + LN2 ----
    f32x4 h2[4] = {};
    #pragma unroll
    for (int kk = 0; kk < 2; kk++)
      #pragma unroll
      for (int t = 0; t < 4; t++) {
        s16x8 wf = *(const s16x8*)(sA1t + SWZ((t * 16 + m) * 128 + g * 16 + kk * 64));
        h2[t] = __builtin_amdgcn_mfma_f32_16x16x32_bf16(
            __builtin_bit_cast(bf16x8, wf), __builtin_bit_cast(bf16x8, bT[kk].v), h2[t], 0, 0, 0);
      }
    #pragma unroll
    for (int t = 0; t < 4; t++) {
      f32x4 ab1 = *(const f32x4*)&sAB1[16 * t + 4 * g];
      #pragma unroll
      for (int r = 0; r < 4; r++) h2[t][r] += ab1[r];
    }
    {
      float s1 = 0.f;
      #pragma unroll
      for (int t = 0; t < 4; t++)
        #pragma unroll
        for (int r = 0; r < 4; r++) s1 += h2[t][r];
      s1 += __shfl_xor(s1, 16); s1 += __shfl_xor(s1, 32);
      float mean = s1 * (1.f / 64.f);
      float qv = 0.f;
      #pragma unroll
      for (int t = 0; t < 4; t++)
        #pragma unroll
        for (int r = 0; r < 4; r++) { float dd = h2[t][r] - mean; qv = fmaf(dd, dd, qv); }
      qv += __shfl_xor(qv, 16); qv += __shfl_xor(qv, 32);
      float rs = rsqrtf(qv * (1.f / 64.f) + 1e-5f);
      #pragma unroll
      for (int t = 0; t < 4; t++) {
        f32x4 gg4 = *(const f32x4*)&sAG[16 * t + 4 * g];
        f32x4 bt4 = *(const f32x4*)&sABeta[16 * t + 4 * g];
        #pragma unroll
        for (int r = 0; r < 4; r++)
          h2[t][r] = fmaxf(fmaf((h2[t][r] - mean) * rs, gg4[r], bt4[r]), 0.f);
      }
    }
    B8 bH[2];
    #pragma unroll
    for (int kk = 0; kk < 2; kk++) {
      bH[kk].u[0] = pack2(h2[2 * kk][0], h2[2 * kk][1]);
      bH[kk].u[1] = pack2(h2[2 * kk][2], h2[2 * kk][3]);
      bH[kk].u[2] = pack2(h2[2 * kk + 1][0], h2[2 * kk + 1][1]);
      bH[kk].u[3] = pack2(h2[2 * kk + 1][2], h2[2 * kk + 1][3]);
    }

    // ---- GEMM3: alpha ----
    f32x4 acc3[4] = {};
    #pragma unroll
    for (int kk = 0; kk < 2; kk++)
      #pragma unroll
      for (int t = 0; t < 4; t++) {
        s16x8 wf = *(const s16x8*)(sA2t + SWZ((t * 16 + m) * 128 + g * 16 + kk * 64));
        acc3[t] = __builtin_amdgcn_mfma_f32_16x16x32_bf16(
            __builtin_bit_cast(bf16x8, wf), __builtin_bit_cast(bf16x8, bH[kk].v), acc3[t], 0, 0, 0);
      }

    // ---- Phase E: exp, weighted values ----
    f32x4 aN[4], aD[4];
    #pragma unroll
    for (int t = 0; t < 4; t++) {
      f32x4 ab2 = *(const f32x4*)&sAB2[16 * t + 4 * g];
      #pragma unroll
      for (int r = 0; r < 4; r++) {
        float e = __expf(acc3[t][r] + ab2[r]);
        e = valid ? e : 0.f;
        aD[t][r] = e;
        aN[t][r] = e * del[t][r];   // v added below from VV
      }
    }
    #pragma unroll
    for (int kk = 0; kk < 2; kk++) {
      float vf[8];
      unpack8(VV[kk], vf);
      #pragma unroll
      for (int j = 0; j < 8; j++) {
        int t = 2 * kk + (j >> 2), r = j & 3;
        aN[t][r] = fmaf(aD[t][r], vf[j], aN[t][r]);
      }
    }

    // ---- segmented scan along m (r5-proven) + tail atomics ----
    int dprev = dppi<0x111>(d, -1);   // row_shr:1
    int dnext = dppi<0x101>(d, -1);   // row_shl:1
    bool head = (d != dprev);
    bool tl   = (d != dnext);
    unsigned long long hb = __ballot(head);
    unsigned mask16 = (unsigned)(hb >> (g * 16)) & 0xFFFFu;
    unsigned maskLE = mask16 & ((1u << (m + 1)) - 1u);
    int hd = m - (31 - __builtin_clz(maskLE | 1u));

    #define SCAN_ROUND(OFF, CTRL)                                        \
      { bool p = hd >= OFF;                                              \
        _Pragma("unroll")                                                \
        for (int t = 0; t < 4; t++) {                                    \
          _Pragma("unroll")                                              \
          for (int r = 0; r < 4; r++) {                                  \
            float shN = dppf<CTRL>(aN[t][r]);                            \
            float shD = dppf<CTRL>(aD[t][r]);                            \
            aN[t][r] += p ? shN : 0.f;                                   \
            aD[t][r] += p ? shD : 0.f;                                   \
          }                                                              \
        } }
    SCAN_ROUND(1, 0x111)
    SCAN_ROUND(2, 0x112)
    SCAN_ROUND(4, 0x114)
    SCAN_ROUND(8, 0x118)
    #undef SCAN_ROUND

    if (valid && tl) {
      #pragma unroll
      for (int t = 0; t < 4; t++)
        #pragma unroll
        for (int r = 0; r < 4; r++) {
          atomicAdd(&numer[(size_t)d * 64 + 16 * t + 4 * g + r], aN[t][r]);
          atomicAdd(&denom[(size_t)d * 64 + 16 * t + 4 * g + r], aD[t][r]);
        }
    }
  }
}

// ---------------- output linear (MFMA) ----------------
__global__ __launch_bounds__(256) void out_mfma_kernel(
    const float* __restrict__ numer, const float* __restrict__ denom,
    const float* __restrict__ W_out, const float* __restrict__ b_out,
    float* __restrict__ out, int N)
{
  __shared__ __align__(16) char sWoT[8192], sX[8192];
  __shared__ float sB[64];
  int tid = threadIdx.x;
  stage_wt(W_out, sWoT, tid);
  if (tid < 64) sB[tid] = b_out[tid];

  const int lane = tid & 63, wv = tid >> 6;
  const int g = lane >> 4, m = lane & 15;
  const int ew = wv << 4;
  const int srow = tid >> 2, sc0 = (tid & 3) << 4;
  const int ntile = (N + 63) >> 6;

  for (int tile = blockIdx.x; tile < ntile; tile += gridDim.x) {
    const int rbase = tile << 6;
    __syncthreads();
    {
      int gr = rbase + srow; if (gr >= N) gr = N - 1;
      const float4* nsrc = (const float4*)&numer[(size_t)gr * 64 + sc0];
      const float4* dsrc = (const float4*)&denom[(size_t)gr * 64 + sc0];
      #pragma unroll
      for (int q = 0; q < 4; q++) {
        float4 fn = nsrc[q], fd = dsrc[q];
        float m0 = fn.x / fmaxf(fd.x, 1e-16f);
        float m1 = fn.y / fmaxf(fd.y, 1e-16f);
        float m2 = fn.z / fmaxf(fd.z, 1e-16f);
        float m3 = fn.w / fmaxf(fd.w, 1e-16f);
        int byte = srow * 128 + sc0 * 2 + q * 8;
        *(unsigned int*)(sX + SWZ(byte))     = pack2(m0, m1);
        *(unsigned int*)(sX + SWZ(byte + 4)) = pack2(m2, m3);
      }
    }
    __syncthreads();
    f32x4 acc[4] = {};
    gemm16(sX + ew * 128, sWoT, g, m, acc);
    #pragma unroll
    for (int t = 0; t < 4; t++)
      #pragma unroll
      for (int r = 0; r < 4; r++) {
        int gr = rbase + ew + 4 * g + r;
        if (gr < N) out[(size_t)gr * 64 + t * 16 + m] = fmaxf(acc[t][r] + sB[t * 16 + m], 0.f);
      }
  }
}

extern "C" void kernel_launch(void* const* d_in, const int* in_sizes, int n_in,
                              void* d_out, int out_size, void* d_ws, size_t ws_size,
                              hipStream_t stream) {
  (void)n_in; (void)out_size; (void)ws_size;
  const float* x        = (const float*)d_in[0];
  const float* pos      = (const float*)d_in[1];
  const int*   ei       = (const int*)  d_in[2];
  const float* W_in     = (const float*)d_in[3];
  const float* b_in     = (const float*)d_in[4];
  const float* W_lin    = (const float*)d_in[5];
  const float* W_src    = (const float*)d_in[6];
  const float* W_dst    = (const float*)d_in[7];
  const float* pos_W1   = (const float*)d_in[8];
  const float* pos_b1   = (const float*)d_in[9];
  const float* pos_g    = (const float*)d_in[10];
  const float* pos_beta = (const float*)d_in[11];
  const float* pos_W2   = (const float*)d_in[12];
  const float* pos_b2   = (const float*)d_in[13];
  const float* att_W1   = (const float*)d_in[14];
  const float* att_b1   = (const float*)d_in[15];
  const float* att_g    = (const float*)d_in[16];
  const float* att_beta = (const float*)d_in[17];
  const float* att_W2   = (const float*)d_in[18];
  const float* att_b2   = (const float*)d_in[19];
  const float* W_out    = (const float*)d_in[20];
  const float* b_out    = (const float*)d_in[21];

  const int N    = in_sizes[0] / 64;
  const int E    = in_sizes[2] / 2;
  const int Etot = E + N;
  const int Epad = (Etot + 15) & ~15;
  const size_t N64 = (size_t)N * 64;

  float* numer = (float*)d_ws;
  float* denom = numer + N64;
  unsigned short* aSb = (unsigned short*)(denom + N64);
  unsigned short* aDb = aSb + N64;
  unsigned short* vBb = aDb + N64;
  float4* pd4 = (float4*)(vBb + N64);
  int* srcS     = (int*)(pd4 + Epad);
  int* dstS     = srcS + Epad;
  int* deg      = dstS + Epad;
  int* cursor   = deg + N;
  int* chunkSum = cursor + N;
  int* chunkPre = chunkSum + 256;

  const int nchunk = (N + 255) / 256;

  hipMemsetAsync(deg, 0, (size_t)N * sizeof(int), stream);
  hipMemsetAsync(numer, 0, 2 * N64 * sizeof(float), stream);
  if (Epad > Etot) {
    hipMemsetAsync(dstS + Etot, 0xFF, (size_t)(Epad - Etot) * sizeof(int), stream);
    hipMemsetAsync(srcS + Etot, 0, (size_t)(Epad - Etot) * sizeof(int), stream);
    hipMemsetAsync(pd4 + Etot, 0, (size_t)(Epad - Etot) * sizeof(float4), stream);
  }

  hist_kernel<<<1024, 256, 0, stream>>>(ei, deg, E, Etot);
  scanA_kernel<<<nchunk, 256, 0, stream>>>(deg, chunkSum, N);
  scanB_kernel<<<1, 256, 0, stream>>>(chunkSum, chunkPre, nchunk);
  scanC_kernel<<<nchunk, 256, 0, stream>>>(deg, chunkPre, cursor, N);
  scatter_kernel<<<1024, 256, 0, stream>>>(ei, cursor, pos, srcS, dstS, pd4, E, Etot);

  const int ntileN = (N + 63) / 64;
  const int nblkN  = ntileN < 768 ? ntileN : 768;
  node_mfma_kernel<<<nblkN, 256, 0, stream>>>(x, W_in, b_in, W_lin, W_src, W_dst,
                                              aSb, aDb, vBb, N);

  const int G   = Epad / 16;
  const int NB  = 768;
  const int gpw = (G + NB * 4 - 1) / (NB * 4);
  edge_kernel<<<NB, 256, 0, stream>>>(srcS, dstS, pd4, aSb, aDb, vBb,
      pos_W1, pos_b1, pos_g, pos_beta, pos_W2, pos_b2,
      att_W1, att_b1, att_g, att_beta, att_W2, att_b2,
      numer, denom, G, gpw);

  out_mfma_kernel<<<nblkN, 256, 0, stream>>>(numer, denom, W_out, b_out, (float*)d_out, N);
}

// Round 15
// 450.429 us; speedup vs baseline: 1.3768x; 1.3768x over previous
//
#include <hip/hip_runtime.h>
#include <hip/hip_bf16.h>

// PointTransformerBlock, round 15: r8 (best: 431us) + a_src/v interleave.
//   r8 analysis: edge kernel is random-small-granule memory bound
//   (FETCH 502MB @ ~1.7TB/s effective == 300us edge dur). This round merges
//   a_src and v (same gather index s) into one interleaved array avB:
//   av[s*128 + 8*(c>>2) + (c&3)] = a_src ch c ; +4 = v ch c.
//   Each lane's as+vv gather becomes ONE 16B load from one cache line;
//   per-edge random streams drop 3 -> 2. Everything else identical to r8.

typedef __bf16 bf16x8 __attribute__((ext_vector_type(8)));
typedef short  s16x8  __attribute__((ext_vector_type(8)));
typedef float  f32x4  __attribute__((ext_vector_type(4)));

#define SWZ(b) ((b) ^ ((((b) >> 7) & 7) << 4))

__device__ __forceinline__ unsigned short f2b(float f) {
  union { __hip_bfloat16 h; unsigned short u; } c;
  c.h = __float2bfloat16(f);
  return c.u;
}
__device__ __forceinline__ unsigned int pack2(float a, float b) {
  return (unsigned int)f2b(a) | ((unsigned int)f2b(b) << 16);
}
__device__ __forceinline__ void unpack2(unsigned int u, float& a, float& b) {
  union { unsigned int x; float f; } t0, t1;
  t0.x = u << 16; t1.x = u & 0xffff0000u;
  a = t0.f; b = t1.f;
}
__device__ __forceinline__ void lds_fence() {
  asm volatile("s_waitcnt lgkmcnt(0)" ::: "memory");
  __builtin_amdgcn_sched_barrier(0);
}
__device__ __forceinline__ f32x4 psel(bool p, f32x4 a) {
  f32x4 z = {0.f, 0.f, 0.f, 0.f};
  return p ? a : z;
}
template <int D>
__device__ __forceinline__ f32x4 shup4(f32x4 v) {
  f32x4 r;
  #pragma unroll
  for (int c = 0; c < 4; c++) r[c] = __shfl_up(v[c], D);
  return r;
}

__device__ __forceinline__ int sigp(int p) { return 4 * (p & 15) + (p >> 4); }

// plain staging: W[k][c] -> W^T [c][k] bf16, swizzled (node/out kernels)
__device__ __forceinline__ void stage_wt(const float* __restrict__ W, char* dst, int tid) {
  for (int idx = tid; idx < 2048; idx += 256) {
    int c  = idx >> 5;
    int k2 = (idx & 31) << 1;
    *(unsigned int*)(dst + SWZ(c * 128 + k2 * 2)) = pack2(W[k2 * 64 + c], W[(k2 + 1) * 64 + c]);
  }
}
// sigma staging: position (q,p) holds W[sig(p)][sig(q)]
__device__ __forceinline__ void stage_wt_sig(const float* __restrict__ W, char* dst, int tid) {
  for (int idx = tid; idx < 2048; idx += 256) {
    int q  = idx >> 5;
    int p2 = (idx & 31) << 1;
    int co = sigp(q);
    *(unsigned int*)(dst + SWZ(q * 128 + p2 * 2)) =
        pack2(W[sigp(p2) * 64 + co], W[sigp(p2 + 1) * 64 + co]);
  }
}

// 16-row tile GEMM (A = act rows from LDS), acc[t] = cols t*16..t*16+15
__device__ __forceinline__ void gemm16(const char* actb, const char* wb,
                                       int g, int m, f32x4 acc[4]) {
  #pragma unroll
  for (int kk = 0; kk < 2; kk++) {
    s16x8 af = *(const s16x8*)(actb + SWZ(m * 128 + g * 16 + kk * 64));
    #pragma unroll
    for (int t = 0; t < 4; t++) {
      s16x8 bf = *(const s16x8*)(wb + SWZ((t * 16 + m) * 128 + g * 16 + kk * 64));
      acc[t] = __builtin_amdgcn_mfma_f32_16x16x32_bf16(
          __builtin_bit_cast(bf16x8, af), __builtin_bit_cast(bf16x8, bf), acc[t], 0, 0, 0);
    }
  }
}

// ---------------- node linears (MFMA), bf16 outputs ----------------
// a_dst -> a_dstB plain channel order; a_src & v -> avB interleaved:
//   avB[node*128 + 32t + 8*(m>>2) + (m&3)]     = a_src ch (16t+m)
//   avB[node*128 + 32t + 8*(m>>2) + 4 + (m&3)] = v     ch (16t+m)
__global__ __launch_bounds__(256, 3) void node_mfma_kernel(
    const float* __restrict__ x,
    const float* __restrict__ W_in, const float* __restrict__ b_in,
    const float* __restrict__ W_lin, const float* __restrict__ W_src, const float* __restrict__ W_dst,
    unsigned short* __restrict__ avB, unsigned short* __restrict__ a_dstB, int N)
{
  __shared__ __align__(16) char sWinT[8192], sWsT[8192], sWdT[8192], sWlT[8192], sX[8192];
  __shared__ __align__(16) float sB[64];
  int tid = threadIdx.x;
  stage_wt(W_in,  sWinT, tid);
  stage_wt(W_src, sWsT,  tid);
  stage_wt(W_dst, sWdT,  tid);
  stage_wt(W_lin, sWlT,  tid);
  if (tid < 64) sB[tid] = b_in[tid];

  const int lane = tid & 63, wv = tid >> 6;
  const int g = lane >> 4, m = lane & 15;
  const int ew = wv << 4;
  const int srow = tid >> 2, sc0 = (tid & 3) << 4;
  const int ntile = (N + 63) >> 6;

  int pstore[4];
  #pragma unroll
  for (int t = 0; t < 4; t++) pstore[t] = 32 * t + 8 * (m >> 2) + (m & 3);

  for (int tile = blockIdx.x; tile < ntile; tile += gridDim.x) {
    const int rbase = tile << 6;
    __syncthreads();
    {
      int gr = rbase + srow; if (gr >= N) gr = N - 1;
      const float4* src = (const float4*)&x[(size_t)gr * 64 + sc0];
      #pragma unroll
      for (int q = 0; q < 4; q++) {
        float4 f = src[q];
        int byte = srow * 128 + sc0 * 2 + q * 8;
        *(unsigned int*)(sX + SWZ(byte))     = pack2(f.x, f.y);
        *(unsigned int*)(sX + SWZ(byte + 4)) = pack2(f.z, f.w);
      }
    }
    __syncthreads();

    f32x4 a0[4] = {};
    gemm16(sX + ew * 128, sWinT, g, m, a0);
    float x1[4][4];
    #pragma unroll
    for (int t = 0; t < 4; t++)
      #pragma unroll
      for (int r = 0; r < 4; r++) x1[t][r] = fmaxf(a0[t][r] + sB[t * 16 + m], 0.f);
    __syncthreads();
    #pragma unroll
    for (int t = 0; t < 4; t++)
      #pragma unroll
      for (int r = 0; r < 4; r++)
        *(unsigned short*)(sX + SWZ((ew + 4 * g + r) * 128 + (t * 16 + m) * 2)) = f2b(x1[t][r]);
    __syncthreads();

    f32x4 as[4] = {}, ad[4] = {}, al[4] = {};
    gemm16(sX + ew * 128, sWsT, g, m, as);
    gemm16(sX + ew * 128, sWdT, g, m, ad);
    gemm16(sX + ew * 128, sWlT, g, m, al);
    #pragma unroll
    for (int t = 0; t < 4; t++)
      #pragma unroll
      for (int r = 0; r < 4; r++) {
        int gr = rbase + ew + 4 * g + r;
        if (gr < N) {
          a_dstB[(size_t)gr * 64 + t * 16 + m] = f2b(ad[t][r]);
          size_t ob = (size_t)gr * 128 + pstore[t];
          avB[ob]     = f2b(as[t][r]);
          avB[ob + 4] = f2b(al[t][r]);
        }
      }
  }
}

// ---------------- CSR build ----------------
__global__ void hist_kernel(const int* __restrict__ ei, int* __restrict__ deg, int E, int Etot) {
  int stride = gridDim.x * blockDim.x;
  for (int e = blockIdx.x * blockDim.x + threadIdx.x; e < Etot; e += stride) {
    int d = (e < E) ? ei[E + e] : (e - E);
    atomicAdd(&deg[d], 1);
  }
}

__global__ __launch_bounds__(256) void scanA_kernel(const int* __restrict__ deg, int* __restrict__ chunkSum, int N) {
  __shared__ int s[256];
  int i = blockIdx.x * 256 + threadIdx.x;
  s[threadIdx.x] = (i < N) ? deg[i] : 0;
  __syncthreads();
  for (int off = 128; off > 0; off >>= 1) {
    if (threadIdx.x < off) s[threadIdx.x] += s[threadIdx.x + off];
    __syncthreads();
  }
  if (threadIdx.x == 0) chunkSum[blockIdx.x] = s[0];
}

__global__ __launch_bounds__(256) void scanB_kernel(const int* __restrict__ chunkSum, int* __restrict__ chunkPre, int nchunk) {
  __shared__ int s[256];
  int t = threadIdx.x;
  int v = (t < nchunk) ? chunkSum[t] : 0;
  s[t] = v; __syncthreads();
  for (int off = 1; off < 256; off <<= 1) {
    int x = (t >= off) ? s[t - off] : 0;
    __syncthreads();
    s[t] += x;
    __syncthreads();
  }
  if (t < nchunk) chunkPre[t] = s[t] - v;
}

__global__ __launch_bounds__(256) void scanC_kernel(const int* __restrict__ deg, const int* __restrict__ chunkPre,
                                                    int* __restrict__ cursor, int N) {
  __shared__ int s[256];
  int t = threadIdx.x;
  int i = blockIdx.x * 256 + t;
  int v = (i < N) ? deg[i] : 0;
  s[t] = v; __syncthreads();
  for (int off = 1; off < 256; off <<= 1) {
    int x = (t >= off) ? s[t - off] : 0;
    __syncthreads();
    s[t] += x;
    __syncthreads();
  }
  if (i < N) cursor[i] = chunkPre[blockIdx.x] + s[t] - v;
}

__global__ void scatter_kernel(const int* __restrict__ ei, int* __restrict__ cursor,
                               const float* __restrict__ pos,
                               int* __restrict__ srcS, int* __restrict__ dstS,
                               float4* __restrict__ pd4,
                               int E, int Etot) {
  int stride = gridDim.x * blockDim.x;
  for (int e = blockIdx.x * blockDim.x + threadIdx.x; e < Etot; e += stride) {
    int s, d;
    if (e < E) { s = ei[e]; d = ei[E + e]; }
    else       { s = e - E; d = s; }
    int p = atomicAdd(&cursor[d], 1);
    srcS[p] = s; dstS[p] = d;
    float4 q;
    q.x = pos[d * 3 + 0] - pos[s * 3 + 0];
    q.y = pos[d * 3 + 1] - pos[s * 3 + 1];
    q.z = pos[d * 3 + 2] - pos[s * 3 + 2];
    q.w = 0.f;
    pd4[p] = q;
  }
}

// ---------------- pipelined fused edge kernel ----------------
struct Meta { int md[4]; int ms[4]; f32x4 pd[4]; };
struct Gath { uint2 ad[4]; uint4 asvv[4]; };   // asvv: .x.y = a_src 4m..4m+3, .z.w = v

__device__ __forceinline__ Meta load_meta(const int* __restrict__ dstS, const int* __restrict__ srcS,
                                          const float4* __restrict__ pd4, int ebase, int g) {
  Meta M;
  int4 a = *(const int4*)&dstS[ebase + 4 * g];
  int4 b = *(const int4*)&srcS[ebase + 4 * g];
  M.md[0] = a.x; M.md[1] = a.y; M.md[2] = a.z; M.md[3] = a.w;
  M.ms[0] = b.x; M.ms[1] = b.y; M.ms[2] = b.z; M.ms[3] = b.w;
  #pragma unroll
  for (int r = 0; r < 4; r++) {
    float4 p = pd4[ebase + 4 * g + r];
    M.pd[r][0] = p.x; M.pd[r][1] = p.y; M.pd[r][2] = p.z; M.pd[r][3] = 0.f;
  }
  return M;
}
__device__ __forceinline__ Gath load_gath(const Meta& M,
                                          const unsigned short* __restrict__ aD,
                                          const unsigned short* __restrict__ avB, int m) {
  Gath G;
  #pragma unroll
  for (int r = 0; r < 4; r++) {
    int dm = M.md[r] < 0 ? 0 : M.md[r];
    G.ad[r]   = *(const uint2*)&aD[(size_t)dm * 64 + 4 * m];
    G.asvv[r] = *(const uint4*)&avB[(size_t)M.ms[r] * 128 + 8 * m];
  }
  return G;
}

__global__ __launch_bounds__(256, 3) void edge_kernel(
    const int* __restrict__ srcS, const int* __restrict__ dstS, const float4* __restrict__ pd4,
    const unsigned short* __restrict__ avB, const unsigned short* __restrict__ a_dstB,
    const float* __restrict__ pos_W1, const float* __restrict__ pos_b1,
    const float* __restrict__ pos_gg, const float* __restrict__ pos_beta,
    const float* __restrict__ pos_W2, const float* __restrict__ pos_b2,
    const float* __restrict__ att_W1, const float* __restrict__ att_b1,
    const float* __restrict__ att_gg, const float* __restrict__ att_beta,
    const float* __restrict__ att_W2, const float* __restrict__ att_b2,
    float* __restrict__ numer, float* __restrict__ denom,
    int G, int gpw)
{
  __shared__ __align__(16) char sW2t[8192], sA1t[8192], sA2t[8192];
  __shared__ __align__(16) char sAct[4][2048];
  __shared__ __align__(16) float sPW1[192];
  __shared__ __align__(16) float sPB1[64], sPG[64], sPBeta[64], sPB2[64];
  __shared__ __align__(16) float sAB1[64], sAG[64], sABeta[64], sAB2[64];

  int tid = threadIdx.x;
  stage_wt_sig(pos_W2, sW2t, tid);
  stage_wt_sig(att_W1, sA1t, tid);
  stage_wt_sig(att_W2, sA2t, tid);
  for (int i = tid; i < 192; i += 256) sPW1[i] = pos_W1[i];
  if (tid < 64) {
    sPB1[tid] = pos_b1[tid]; sPG[tid] = pos_gg[tid]; sPBeta[tid] = pos_beta[tid]; sPB2[tid] = pos_b2[tid];
    sAB1[tid] = att_b1[tid]; sAG[tid] = att_gg[tid]; sABeta[tid] = att_beta[tid]; sAB2[tid] = att_b2[tid];
  }
  __syncthreads();  // only block barrier

  const int lane = tid & 63, wv = tid >> 6;
  const int g = lane >> 4, m = lane & 15;
  char* myAct = sAct[wv];

  const int w  = blockIdx.x * 4 + wv;
  const int g0 = w * gpw;
  int g1 = g0 + gpw; if (g1 > G) g1 = G;
  if (g0 >= g1) return;

  // per-lane constant vectors (sigma channels 4m..4m+3)
  const f32x4 pw0 = *(const f32x4*)&sPW1[4 * m];
  const f32x4 pw1 = *(const f32x4*)&sPW1[64 + 4 * m];
  const f32x4 pw2 = *(const f32x4*)&sPW1[128 + 4 * m];
  const f32x4 pb1 = *(const f32x4*)&sPB1[4 * m];
  const f32x4 pgv = *(const f32x4*)&sPG[4 * m];
  const f32x4 pbv = *(const f32x4*)&sPBeta[4 * m];
  const f32x4 pb2 = *(const f32x4*)&sPB2[4 * m];
  const f32x4 ab1 = *(const f32x4*)&sAB1[4 * m];
  const f32x4 agv = *(const f32x4*)&sAG[4 * m];
  const f32x4 abv = *(const f32x4*)&sABeta[4 * m];
  const f32x4 ab2 = *(const f32x4*)&sAB2[4 * m];

  Meta Mc = load_meta(dstS, srcS, pd4, g0 << 4, g);
  Gath Gc = load_gath(Mc, a_dstB, avB, m);

  for (int grp = g0; grp < g1; ++grp) {
    const int gnext = (grp + 1 < g1) ? grp + 1 : grp;
    Meta Mn = load_meta(dstS, srcS, pd4, gnext << 4, g);   // issue early

    // ---- Phase A: h = relu(LN(pd @ posW1 + b1)), lane holds ch 4m+t ----
    f32x4 hA[4];
    #pragma unroll
    for (int r = 0; r < 4; r++) {
      f32x4 h = pb1 + pw0 * Mc.pd[r][0] + pw1 * Mc.pd[r][1] + pw2 * Mc.pd[r][2];
      float s = h[0] + h[1] + h[2] + h[3];
      s += __shfl_xor(s, 1); s += __shfl_xor(s, 2); s += __shfl_xor(s, 4); s += __shfl_xor(s, 8);
      float mean = s * (1.f / 64.f);
      f32x4 dv = h - mean;
      float q = dv[0]*dv[0] + dv[1]*dv[1] + dv[2]*dv[2] + dv[3]*dv[3];
      q += __shfl_xor(q, 1); q += __shfl_xor(q, 2); q += __shfl_xor(q, 4); q += __shfl_xor(q, 8);
      float rs = rsqrtf(q * (1.f / 64.f) + 1e-5f);
      f32x4 o = dv * rs * pgv + pbv;
      #pragma unroll
      for (int c = 0; c < 4; c++) o[c] = fmaxf(o[c], 0.f);
      hA[r] = o;
    }
    #pragma unroll
    for (int r = 0; r < 4; r++)
      #pragma unroll
      for (int t = 0; t < 4; t++)
        *(unsigned short*)(myAct + SWZ((4 * g + r) * 128 + 32 * t + 2 * m)) = f2b(hA[r][t]);
    lds_fence();

    // ---- GEMM1: delta ----
    f32x4 dacc[4] = {};
    gemm16(myAct, sW2t, g, m, dacc);
    f32x4 del[4];
    #pragma unroll
    for (int t = 0; t < 4; t++) del[t] = dacc[t] + pb2[t];

    // ---- attin = a_dst - a_src + delta -> LDS (WAR safe: DS in-order) ----
    #pragma unroll
    for (int r = 0; r < 4; r++) {
      float da[4], sa[4];
      unpack2(Gc.ad[r].x, da[0], da[1]);   unpack2(Gc.ad[r].y, da[2], da[3]);
      unpack2(Gc.asvv[r].x, sa[0], sa[1]); unpack2(Gc.asvv[r].y, sa[2], sa[3]);
      #pragma unroll
      for (int t = 0; t < 4; t++) {
        float av = da[t] - sa[t] + del[t][r];
        *(unsigned short*)(myAct + SWZ((4 * g + r) * 128 + 32 * t + 2 * m)) = f2b(av);
      }
    }
    lds_fence();

    // ---- GEMM2 + LN2 ----
    f32x4 acc2[4] = {};
    gemm16(myAct, sA1t, g, m, acc2);
    f32x4 h2[4];
    #pragma unroll
    for (int t = 0; t < 4; t++) h2[t] = acc2[t] + ab1[t];
    #pragma unroll
    for (int r = 0; r < 4; r++) {
      float s = h2[0][r] + h2[1][r] + h2[2][r] + h2[3][r];
      s += __shfl_xor(s, 1); s += __shfl_xor(s, 2); s += __shfl_xor(s, 4); s += __shfl_xor(s, 8);
      float mean = s * (1.f / 64.f);
      float q = 0.f;
      #pragma unroll
      for (int t = 0; t < 4; t++) { float dd = h2[t][r] - mean; q = fmaf(dd, dd, q); }
      q += __shfl_xor(q, 1); q += __shfl_xor(q, 2); q += __shfl_xor(q, 4); q += __shfl_xor(q, 8);
      float rs = rsqrtf(q * (1.f / 64.f) + 1e-5f);
      #pragma unroll
      for (int t = 0; t < 4; t++)
        h2[t][r] = fmaxf(fmaf((h2[t][r] - mean) * rs, agv[t], abv[t]), 0.f);
    }
    #pragma unroll
    for (int r = 0; r < 4; r++)
      #pragma unroll
      for (int t = 0; t < 4; t++)
        *(unsigned short*)(myAct + SWZ((4 * g + r) * 128 + 32 * t + 2 * m)) = f2b(h2[t][r]);
    lds_fence();

    // ---- GEMM3: alpha ----
    f32x4 acc3[4] = {};
    gemm16(myAct, sA2t, g, m, acc3);

    // ---- prefetch next group's gathers (hidden under phase E + next A) ----
    Gath Gn = load_gath(Mn, a_dstB, avB, m);

    // ---- Phase E: exp, weighted values ----
    f32x4 nV[4], dV[4];
    #pragma unroll
    for (int r = 0; r < 4; r++) {
      float vf[4];
      unpack2(Gc.asvv[r].z, vf[0], vf[1]); unpack2(Gc.asvv[r].w, vf[2], vf[3]);
      bool val = Mc.md[r] >= 0;
      #pragma unroll
      for (int t = 0; t < 4; t++) {
        float e = __expf(acc3[t][r] + ab2[t]);
        e = val ? e : 0.f;
        nV[r][t] = e * (vf[t] + del[t][r]);
        dV[r][t] = e;
      }
    }

    // ---- segmented reduce: suffix partial + carry scan + tail flush ----
    // ALL shfls unconditional (convergent ops must not sit inside &&).
    {
      int d3 = Mc.md[3];
      bool s2 = (Mc.md[2] == d3);
      bool s1 = s2 && (Mc.md[1] == d3);
      bool s0 = s1 && (Mc.md[0] == d3);
      f32x4 PN = nV[3] + psel(s2, nV[2]) + psel(s1, nV[1]) + psel(s0, nV[0]);
      f32x4 PD = dV[3] + psel(s2, dV[2]) + psel(s1, dV[1]) + psel(s0, dV[0]);

      int dPrev3 = __shfl_up(d3, 16);
      int dNext0 = __shfl_down(Mc.md[0], 16);
      bool ok1 = (g > 0) && (Mc.md[0] == dPrev3);
      int okf = (ok1 && s0) ? 1 : 0;
      int okf1 = __shfl_up(okf, 16);   // unconditional
      int okf2 = __shfl_up(okf, 32);   // unconditional
      bool ok2 = ok1 && (okf1 != 0);
      bool ok3 = ok2 && (okf2 != 0);
      f32x4 sh16N = shup4<16>(PN), sh32N = shup4<32>(PN), sh48N = shup4<48>(PN);
      f32x4 sh16D = shup4<16>(PD), sh32D = shup4<32>(PD), sh48D = shup4<48>(PD);
      f32x4 CN = psel(ok1, sh16N) + psel(ok2, sh32N) + psel(ok3, sh48N);
      f32x4 CD = psel(ok1, sh16D) + psel(ok2, sh32D) + psel(ok3, sh48D);

      int dn[4] = { Mc.md[1], Mc.md[2], Mc.md[3], (g == 3) ? (int)0x80000000 : dNext0 };

      f32x4 aN = CN, aD = CD;
      #pragma unroll
      for (int r = 0; r < 4; r++) {
        aN += nV[r]; aD += dV[r];
        if (Mc.md[r] != dn[r]) {
          if (Mc.md[r] >= 0) {
            float* np = &numer[(size_t)Mc.md[r] * 64 + 4 * m];
            float* dp = &denom[(size_t)Mc.md[r] * 64 + 4 * m];
            #pragma unroll
            for (int t = 0; t < 4; t++) { atomicAdd(np + t, aN[t]); atomicAdd(dp + t, aD[t]); }
          }
          f32x4 z = {0.f, 0.f, 0.f, 0.f};
          aN = z; aD = z;
        }
      }
    }

    Mc = Mn; Gc = Gn;
  }
}

// ---------------- output linear (MFMA) ----------------
__global__ __launch_bounds__(256) void out_mfma_kernel(
    const float* __restrict__ numer, const float* __restrict__ denom,
    const float* __restrict__ W_out, const float* __restrict__ b_out,
    float* __restrict__ out, int N)
{
  __shared__ __align__(16) char sWoT[8192], sX[8192];
  __shared__ float sB[64];
  int tid = threadIdx.x;
  stage_wt(W_out, sWoT, tid);
  if (tid < 64) sB[tid] = b_out[tid];

  const int lane = tid & 63, wv = tid >> 6;
  const int g = lane >> 4, m = lane & 15;
  const int ew = wv << 4;
  const int srow = tid >> 2, sc0 = (tid & 3) << 4;
  const int ntile = (N + 63) >> 6;

  for (int tile = blockIdx.x; tile < ntile; tile += gridDim.x) {
    const int rbase = tile << 6;
    __syncthreads();
    {
      int gr = rbase + srow; if (gr >= N) gr = N - 1;
      const float4* nsrc = (const float4*)&numer[(size_t)gr * 64 + sc0];
      const float4* dsrc = (const float4*)&denom[(size_t)gr * 64 + sc0];
      #pragma unroll
      for (int q = 0; q < 4; q++) {
        float4 fn = nsrc[q], fd = dsrc[q];
        float m0 = fn.x / fmaxf(fd.x, 1e-16f);
        float m1 = fn.y / fmaxf(fd.y, 1e-16f);
        float m2 = fn.z / fmaxf(fd.z, 1e-16f);
        float m3 = fn.w / fmaxf(fd.w, 1e-16f);
        int byte = srow * 128 + sc0 * 2 + q * 8;
        *(unsigned int*)(sX + SWZ(byte))     = pack2(m0, m1);
        *(unsigned int*)(sX + SWZ(byte + 4)) = pack2(m2, m3);
      }
    }
    __syncthreads();
    f32x4 acc[4] = {};
    gemm16(sX + ew * 128, sWoT, g, m, acc);
    #pragma unroll
    for (int t = 0; t < 4; t++)
      #pragma unroll
      for (int r = 0; r < 4; r++) {
        int gr = rbase + ew + 4 * g + r;
        if (gr < N) out[(size_t)gr * 64 + t * 16 + m] = fmaxf(acc[t][r] + sB[t * 16 + m], 0.f);
      }
  }
}

extern "C" void kernel_launch(void* const* d_in, const int* in_sizes, int n_in,
                              void* d_out, int out_size, void* d_ws, size_t ws_size,
                              hipStream_t stream) {
  (void)n_in; (void)out_size; (void)ws_size;
  const float* x        = (const float*)d_in[0];
  const float* pos      = (const float*)d_in[1];
  const int*   ei       = (const int*)  d_in[2];
  const float* W_in     = (const float*)d_in[3];
  const float* b_in     = (const float*)d_in[4];
  const float* W_lin    = (const float*)d_in[5];
  const float* W_src    = (const float*)d_in[6];
  const float* W_dst    = (const float*)d_in[7];
  const float* pos_W1   = (const float*)d_in[8];
  const float* pos_b1   = (const float*)d_in[9];
  const float* pos_g    = (const float*)d_in[10];
  const float* pos_beta = (const float*)d_in[11];
  const float* pos_W2   = (const float*)d_in[12];
  const float* pos_b2   = (const float*)d_in[13];
  const float* att_W1   = (const float*)d_in[14];
  const float* att_b1   = (const float*)d_in[15];
  const float* att_g    = (const float*)d_in[16];
  const float* att_beta = (const float*)d_in[17];
  const float* att_W2   = (const float*)d_in[18];
  const float* att_b2   = (const float*)d_in[19];
  const float* W_out    = (const float*)d_in[20];
  const float* b_out    = (const float*)d_in[21];

  const int N    = in_sizes[0] / 64;
  const int E    = in_sizes[2] / 2;
  const int Etot = E + N;
  const int Epad = (Etot + 15) & ~15;
  const size_t N64 = (size_t)N * 64;

  float* numer = (float*)d_ws;
  float* denom = numer + N64;
  unsigned short* avB = (unsigned short*)(denom + N64);   // 2*N64 shorts
  unsigned short* aDb = avB + 2 * N64;
  float4* pd4 = (float4*)(aDb + N64);
  int* srcS     = (int*)(pd4 + Epad);
  int* dstS     = srcS + Epad;
  int* deg      = dstS + Epad;
  int* cursor   = deg + N;
  int* chunkSum = cursor + N;
  int* chunkPre = chunkSum + 256;

  const int nchunk = (N + 255) / 256;

  hipMemsetAsync(deg, 0, (size_t)N * sizeof(int), stream);
  hipMemsetAsync(numer, 0, 2 * N64 * sizeof(float), stream);
  if (Epad > Etot) {
    hipMemsetAsync(dstS + Etot, 0xFF, (size_t)(Epad - Etot) * sizeof(int), stream);
    hipMemsetAsync(srcS + Etot, 0, (size_t)(Epad - Etot) * sizeof(int), stream);
    hipMemsetAsync(pd4 + Etot, 0, (size_t)(Epad - Etot) * sizeof(float4), stream);
  }

  hist_kernel<<<1024, 256, 0, stream>>>(ei, deg, E, Etot);
  scanA_kernel<<<nchunk, 256, 0, stream>>>(deg, chunkSum, N);
  scanB_kernel<<<1, 256, 0, stream>>>(chunkSum, chunkPre, nchunk);
  scanC_kernel<<<nchunk, 256, 0, stream>>>(deg, chunkPre, cursor, N);
  scatter_kernel<<<1024, 256, 0, stream>>>(ei, cursor, pos, srcS, dstS, pd4, E, Etot);

  const int ntileN = (N + 63) / 64;
  const int nblkN  = ntileN < 768 ? ntileN : 768;
  node_mfma_kernel<<<nblkN, 256, 0, stream>>>(x, W_in, b_in, W_lin, W_src, W_dst,
                                              avB, aDb, N);

  const int G   = Epad / 16;
  const int NB  = 768;
  const int gpw = (G + NB * 4 - 1) / (NB * 4);
  edge_kernel<<<NB, 256, 0, stream>>>(srcS, dstS, pd4, avB, aDb,
      pos_W1, pos_b1, pos_g, pos_beta, pos_W2, pos_b2,
      att_W1, att_b1, att_g, att_beta, att_W2, att_b2,
      numer, denom, G, gpw);

  out_mfma_kernel<<<nblkN, 256, 0, stream>>>(numer, denom, W_out, b_out, (float*)d_out, N);
}

// Round 16
// 430.835 us; speedup vs baseline: 1.4394x; 1.0455x over previous
//
#include <hip/hip_runtime.h>
#include <hip/hip_bf16.h>

// PointTransformerConv block, FINAL (= round 8, session best: 431us).
//   Channel re-mapping: D-frag position (t,m) <-> semantic channel 4m+t
//   (sigma). Weights staged with sigma on both K-rows and out-cols, so the
//   per-lane channel quartet {4m..4m+3} is CONTIGUOUS -> every gather is one
//   uint2 bf16 load (16 lanes = one 128B coalesced row).
//   Segment merge: per-lane run-reduce + shfl carry-scan across the wave's
//   4 chunks. Carry rule: okf = ok1 && s0 (chunk homogeneous AND connected);
//   ok2 = ok1 && okf(g-1); ok3 = ok2 && okf(g-2).
//   ALL cross-lane shfls hoisted to unconditional straight-line code
//   (convergent ops inside short-circuit && execute under divergent exec ->
//   undefined source-lane reads; r6/r7 failures).
//   r9-r15 post-mortems: DPP-LN/setprio/prefetch-early (+17%), launch-bounds
//   4 waves/EU (spills), 8/16-wave blocks (residency cap), register-chain
//   (VGPR 128), a_src/v interleave (+11% FETCH) -- all regressed vs this.

typedef __bf16 bf16x8 __attribute__((ext_vector_type(8)));
typedef short  s16x8  __attribute__((ext_vector_type(8)));
typedef float  f32x4  __attribute__((ext_vector_type(4)));

#define SWZ(b) ((b) ^ ((((b) >> 7) & 7) << 4))

__device__ __forceinline__ unsigned short f2b(float f) {
  union { __hip_bfloat16 h; unsigned short u; } c;
  c.h = __float2bfloat16(f);
  return c.u;
}
__device__ __forceinline__ unsigned int pack2(float a, float b) {
  return (unsigned int)f2b(a) | ((unsigned int)f2b(b) << 16);
}
__device__ __forceinline__ void unpack2(unsigned int u, float& a, float& b) {
  union { unsigned int x; float f; } t0, t1;
  t0.x = u << 16; t1.x = u & 0xffff0000u;
  a = t0.f; b = t1.f;
}
__device__ __forceinline__ void lds_fence() {
  asm volatile("s_waitcnt lgkmcnt(0)" ::: "memory");
  __builtin_amdgcn_sched_barrier(0);
}
__device__ __forceinline__ f32x4 psel(bool p, f32x4 a) {
  f32x4 z = {0.f, 0.f, 0.f, 0.f};
  return p ? a : z;
}
template <int D>
__device__ __forceinline__ f32x4 shup4(f32x4 v) {
  f32x4 r;
  #pragma unroll
  for (int c = 0; c < 4; c++) r[c] = __shfl_up(v[c], D);
  return r;
}

__device__ __forceinline__ int sigp(int p) { return 4 * (p & 15) + (p >> 4); }

// plain staging: W[k][c] -> W^T [c][k] bf16, swizzled (node/out kernels)
__device__ __forceinline__ void stage_wt(const float* __restrict__ W, char* dst, int tid) {
  for (int idx = tid; idx < 2048; idx += 256) {
    int c  = idx >> 5;
    int k2 = (idx & 31) << 1;
    *(unsigned int*)(dst + SWZ(c * 128 + k2 * 2)) = pack2(W[k2 * 64 + c], W[(k2 + 1) * 64 + c]);
  }
}
// sigma staging: position (q,p) holds W[sig(p)][sig(q)]
__device__ __forceinline__ void stage_wt_sig(const float* __restrict__ W, char* dst, int tid) {
  for (int idx = tid; idx < 2048; idx += 256) {
    int q  = idx >> 5;
    int p2 = (idx & 31) << 1;
    int co = sigp(q);
    *(unsigned int*)(dst + SWZ(q * 128 + p2 * 2)) =
        pack2(W[sigp(p2) * 64 + co], W[sigp(p2 + 1) * 64 + co]);
  }
}

// 16-row tile GEMM (A = act rows from LDS), acc[t] = cols t*16..t*16+15
__device__ __forceinline__ void gemm16(const char* actb, const char* wb,
                                       int g, int m, f32x4 acc[4]) {
  #pragma unroll
  for (int kk = 0; kk < 2; kk++) {
    s16x8 af = *(const s16x8*)(actb + SWZ(m * 128 + g * 16 + kk * 64));
    #pragma unroll
    for (int t = 0; t < 4; t++) {
      s16x8 bf = *(const s16x8*)(wb + SWZ((t * 16 + m) * 128 + g * 16 + kk * 64));
      acc[t] = __builtin_amdgcn_mfma_f32_16x16x32_bf16(
          __builtin_bit_cast(bf16x8, af), __builtin_bit_cast(bf16x8, bf), acc[t], 0, 0, 0);
    }
  }
}

// ---------------- node linears (MFMA), bf16 outputs ----------------
__global__ __launch_bounds__(256, 3) void node_mfma_kernel(
    const float* __restrict__ x,
    const float* __restrict__ W_in, const float* __restrict__ b_in,
    const float* __restrict__ W_lin, const float* __restrict__ W_src, const float* __restrict__ W_dst,
    unsigned short* __restrict__ a_srcB, unsigned short* __restrict__ a_dstB,
    unsigned short* __restrict__ vB, int N)
{
  __shared__ __align__(16) char sWinT[8192], sWsT[8192], sWdT[8192], sWlT[8192], sX[8192];
  __shared__ __align__(16) float sB[64];
  int tid = threadIdx.x;
  stage_wt(W_in,  sWinT, tid);
  stage_wt(W_src, sWsT,  tid);
  stage_wt(W_dst, sWdT,  tid);
  stage_wt(W_lin, sWlT,  tid);
  if (tid < 64) sB[tid] = b_in[tid];

  const int lane = tid & 63, wv = tid >> 6;
  const int g = lane >> 4, m = lane & 15;
  const int ew = wv << 4;
  const int srow = tid >> 2, sc0 = (tid & 3) << 4;
  const int ntile = (N + 63) >> 6;

  for (int tile = blockIdx.x; tile < ntile; tile += gridDim.x) {
    const int rbase = tile << 6;
    __syncthreads();
    {
      int gr = rbase + srow; if (gr >= N) gr = N - 1;
      const float4* src = (const float4*)&x[(size_t)gr * 64 + sc0];
      #pragma unroll
      for (int q = 0; q < 4; q++) {
        float4 f = src[q];
        int byte = srow * 128 + sc0 * 2 + q * 8;
        *(unsigned int*)(sX + SWZ(byte))     = pack2(f.x, f.y);
        *(unsigned int*)(sX + SWZ(byte + 4)) = pack2(f.z, f.w);
      }
    }
    __syncthreads();

    f32x4 a0[4] = {};
    gemm16(sX + ew * 128, sWinT, g, m, a0);
    float x1[4][4];
    #pragma unroll
    for (int t = 0; t < 4; t++)
      #pragma unroll
      for (int r = 0; r < 4; r++) x1[t][r] = fmaxf(a0[t][r] + sB[t * 16 + m], 0.f);
    __syncthreads();
    #pragma unroll
    for (int t = 0; t < 4; t++)
      #pragma unroll
      for (int r = 0; r < 4; r++)
        *(unsigned short*)(sX + SWZ((ew + 4 * g + r) * 128 + (t * 16 + m) * 2)) = f2b(x1[t][r]);
    __syncthreads();

    f32x4 as[4] = {}, ad[4] = {}, al[4] = {};
    gemm16(sX + ew * 128, sWsT, g, m, as);
    gemm16(sX + ew * 128, sWdT, g, m, ad);
    gemm16(sX + ew * 128, sWlT, g, m, al);
    #pragma unroll
    for (int t = 0; t < 4; t++)
      #pragma unroll
      for (int r = 0; r < 4; r++) {
        int gr = rbase + ew + 4 * g + r;
        if (gr < N) {
          size_t o = (size_t)gr * 64 + t * 16 + m;
          a_srcB[o] = f2b(as[t][r]); a_dstB[o] = f2b(ad[t][r]); vB[o] = f2b(al[t][r]);
        }
      }
  }
}

// ---------------- CSR build ----------------
__global__ void hist_kernel(const int* __restrict__ ei, int* __restrict__ deg, int E, int Etot) {
  int stride = gridDim.x * blockDim.x;
  for (int e = blockIdx.x * blockDim.x + threadIdx.x; e < Etot; e += stride) {
    int d = (e < E) ? ei[E + e] : (e - E);
    atomicAdd(&deg[d], 1);
  }
}

__global__ __launch_bounds__(256) void scanA_kernel(const int* __restrict__ deg, int* __restrict__ chunkSum, int N) {
  __shared__ int s[256];
  int i = blockIdx.x * 256 + threadIdx.x;
  s[threadIdx.x] = (i < N) ? deg[i] : 0;
  __syncthreads();
  for (int off = 128; off > 0; off >>= 1) {
    if (threadIdx.x < off) s[threadIdx.x] += s[threadIdx.x + off];
    __syncthreads();
  }
  if (threadIdx.x == 0) chunkSum[blockIdx.x] = s[0];
}

__global__ __launch_bounds__(256) void scanB_kernel(const int* __restrict__ chunkSum, int* __restrict__ chunkPre, int nchunk) {
  __shared__ int s[256];
  int t = threadIdx.x;
  int v = (t < nchunk) ? chunkSum[t] : 0;
  s[t] = v; __syncthreads();
  for (int off = 1; off < 256; off <<= 1) {
    int x = (t >= off) ? s[t - off] : 0;
    __syncthreads();
    s[t] += x;
    __syncthreads();
  }
  if (t < nchunk) chunkPre[t] = s[t] - v;
}

__global__ __launch_bounds__(256) void scanC_kernel(const int* __restrict__ deg, const int* __restrict__ chunkPre,
                                                    int* __restrict__ cursor, int N) {
  __shared__ int s[256];
  int t = threadIdx.x;
  int i = blockIdx.x * 256 + t;
  int v = (i < N) ? deg[i] : 0;
  s[t] = v; __syncthreads();
  for (int off = 1; off < 256; off <<= 1) {
    int x = (t >= off) ? s[t - off] : 0;
    __syncthreads();
    s[t] += x;
    __syncthreads();
  }
  if (i < N) cursor[i] = chunkPre[blockIdx.x] + s[t] - v;
}

__global__ void scatter_kernel(const int* __restrict__ ei, int* __restrict__ cursor,
                               const float* __restrict__ pos,
                               int* __restrict__ srcS, int* __restrict__ dstS,
                               float4* __restrict__ pd4,
                               int E, int Etot) {
  int stride = gridDim.x * blockDim.x;
  for (int e = blockIdx.x * blockDim.x + threadIdx.x; e < Etot; e += stride) {
    int s, d;
    if (e < E) { s = ei[e]; d = ei[E + e]; }
    else       { s = e - E; d = s; }
    int p = atomicAdd(&cursor[d], 1);
    srcS[p] = s; dstS[p] = d;
    float4 q;
    q.x = pos[d * 3 + 0] - pos[s * 3 + 0];
    q.y = pos[d * 3 + 1] - pos[s * 3 + 1];
    q.z = pos[d * 3 + 2] - pos[s * 3 + 2];
    q.w = 0.f;
    pd4[p] = q;
  }
}

// ---------------- pipelined fused edge kernel ----------------
struct Meta { int md[4]; int ms[4]; f32x4 pd[4]; };
struct Gath { uint2 ad[4]; uint2 as[4]; uint2 vv[4]; };

__device__ __forceinline__ Meta load_meta(const int* __restrict__ dstS, const int* __restrict__ srcS,
                                          const float4* __restrict__ pd4, int ebase, int g) {
  Meta M;
  int4 a = *(const int4*)&dstS[ebase + 4 * g];
  int4 b = *(const int4*)&srcS[ebase + 4 * g];
  M.md[0] = a.x; M.md[1] = a.y; M.md[2] = a.z; M.md[3] = a.w;
  M.ms[0] = b.x; M.ms[1] = b.y; M.ms[2] = b.z; M.ms[3] = b.w;
  #pragma unroll
  for (int r = 0; r < 4; r++) {
    float4 p = pd4[ebase + 4 * g + r];
    M.pd[r][0] = p.x; M.pd[r][1] = p.y; M.pd[r][2] = p.z; M.pd[r][3] = 0.f;
  }
  return M;
}
__device__ __forceinline__ Gath load_gath(const Meta& M,
                                          const unsigned short* __restrict__ aD,
                                          const unsigned short* __restrict__ aS,
                                          const unsigned short* __restrict__ vB, int m) {
  Gath G;
  #pragma unroll
  for (int r = 0; r < 4; r++) {
    int dm = M.md[r] < 0 ? 0 : M.md[r];
    G.ad[r] = *(const uint2*)&aD[(size_t)dm * 64 + 4 * m];
    G.as[r] = *(const uint2*)&aS[(size_t)M.ms[r] * 64 + 4 * m];
    G.vv[r] = *(const uint2*)&vB[(size_t)M.ms[r] * 64 + 4 * m];
  }
  return G;
}

__global__ __launch_bounds__(256, 3) void edge_kernel(
    const int* __restrict__ srcS, const int* __restrict__ dstS, const float4* __restrict__ pd4,
    const unsigned short* __restrict__ a_srcB, const unsigned short* __restrict__ a_dstB,
    const unsigned short* __restrict__ vBg,
    const float* __restrict__ pos_W1, const float* __restrict__ pos_b1,
    const float* __restrict__ pos_gg, const float* __restrict__ pos_beta,
    const float* __restrict__ pos_W2, const float* __restrict__ pos_b2,
    const float* __restrict__ att_W1, const float* __restrict__ att_b1,
    const float* __restrict__ att_gg, const float* __restrict__ att_beta,
    const float* __restrict__ att_W2, const float* __restrict__ att_b2,
    float* __restrict__ numer, float* __restrict__ denom,
    int G, int gpw)
{
  __shared__ __align__(16) char sW2t[8192], sA1t[8192], sA2t[8192];
  __shared__ __align__(16) char sAct[4][2048];
  __shared__ __align__(16) float sPW1[192];
  __shared__ __align__(16) float sPB1[64], sPG[64], sPBeta[64], sPB2[64];
  __shared__ __align__(16) float sAB1[64], sAG[64], sABeta[64], sAB2[64];

  int tid = threadIdx.x;
  stage_wt_sig(pos_W2, sW2t, tid);
  stage_wt_sig(att_W1, sA1t, tid);
  stage_wt_sig(att_W2, sA2t, tid);
  for (int i = tid; i < 192; i += 256) sPW1[i] = pos_W1[i];
  if (tid < 64) {
    sPB1[tid] = pos_b1[tid]; sPG[tid] = pos_gg[tid]; sPBeta[tid] = pos_beta[tid]; sPB2[tid] = pos_b2[tid];
    sAB1[tid] = att_b1[tid]; sAG[tid] = att_gg[tid]; sABeta[tid] = att_beta[tid]; sAB2[tid] = att_b2[tid];
  }
  __syncthreads();  // only block barrier

  const int lane = tid & 63, wv = tid >> 6;
  const int g = lane >> 4, m = lane & 15;
  char* myAct = sAct[wv];

  const int w  = blockIdx.x * 4 + wv;
  const int g0 = w * gpw;
  int g1 = g0 + gpw; if (g1 > G) g1 = G;
  if (g0 >= g1) return;

  // per-lane constant vectors (sigma channels 4m..4m+3)
  const f32x4 pw0 = *(const f32x4*)&sPW1[4 * m];
  const f32x4 pw1 = *(const f32x4*)&sPW1[64 + 4 * m];
  const f32x4 pw2 = *(const f32x4*)&sPW1[128 + 4 * m];
  const f32x4 pb1 = *(const f32x4*)&sPB1[4 * m];
  const f32x4 pgv = *(const f32x4*)&sPG[4 * m];
  const f32x4 pbv = *(const f32x4*)&sPBeta[4 * m];
  const f32x4 pb2 = *(const f32x4*)&sPB2[4 * m];
  const f32x4 ab1 = *(const f32x4*)&sAB1[4 * m];
  const f32x4 agv = *(const f32x4*)&sAG[4 * m];
  const f32x4 abv = *(const f32x4*)&sABeta[4 * m];
  const f32x4 ab2 = *(const f32x4*)&sAB2[4 * m];

  Meta Mc = load_meta(dstS, srcS, pd4, g0 << 4, g);
  Gath Gc = load_gath(Mc, a_dstB, a_srcB, vBg, m);

  for (int grp = g0; grp < g1; ++grp) {
    const int gnext = (grp + 1 < g1) ? grp + 1 : grp;
    Meta Mn = load_meta(dstS, srcS, pd4, gnext << 4, g);   // issue early

    // ---- Phase A: h = relu(LN(pd @ posW1 + b1)), lane holds ch 4m+t ----
    f32x4 hA[4];
    #pragma unroll
    for (int r = 0; r < 4; r++) {
      f32x4 h = pb1 + pw0 * Mc.pd[r][0] + pw1 * Mc.pd[r][1] + pw2 * Mc.pd[r][2];
      float s = h[0] + h[1] + h[2] + h[3];
      s += __shfl_xor(s, 1); s += __shfl_xor(s, 2); s += __shfl_xor(s, 4); s += __shfl_xor(s, 8);
      float mean = s * (1.f / 64.f);
      f32x4 dv = h - mean;
      float q = dv[0]*dv[0] + dv[1]*dv[1] + dv[2]*dv[2] + dv[3]*dv[3];
      q += __shfl_xor(q, 1); q += __shfl_xor(q, 2); q += __shfl_xor(q, 4); q += __shfl_xor(q, 8);
      float rs = rsqrtf(q * (1.f / 64.f) + 1e-5f);
      f32x4 o = dv * rs * pgv + pbv;
      #pragma unroll
      for (int c = 0; c < 4; c++) o[c] = fmaxf(o[c], 0.f);
      hA[r] = o;
    }
    #pragma unroll
    for (int r = 0; r < 4; r++)
      #pragma unroll
      for (int t = 0; t < 4; t++)
        *(unsigned short*)(myAct + SWZ((4 * g + r) * 128 + 32 * t + 2 * m)) = f2b(hA[r][t]);
    lds_fence();

    // ---- GEMM1: delta ----
    f32x4 dacc[4] = {};
    gemm16(myAct, sW2t, g, m, dacc);
    f32x4 del[4];
    #pragma unroll
    for (int t = 0; t < 4; t++) del[t] = dacc[t] + pb2[t];

    // ---- attin = a_dst - a_src + delta -> LDS (WAR safe: DS in-order) ----
    #pragma unroll
    for (int r = 0; r < 4; r++) {
      float da[4], sa[4];
      unpack2(Gc.ad[r].x, da[0], da[1]); unpack2(Gc.ad[r].y, da[2], da[3]);
      unpack2(Gc.as[r].x, sa[0], sa[1]); unpack2(Gc.as[r].y, sa[2], sa[3]);
      #pragma unroll
      for (int t = 0; t < 4; t++) {
        float av = da[t] - sa[t] + del[t][r];
        *(unsigned short*)(myAct + SWZ((4 * g + r) * 128 + 32 * t + 2 * m)) = f2b(av);
      }
    }
    lds_fence();

    // ---- GEMM2 + LN2 ----
    f32x4 acc2[4] = {};
    gemm16(myAct, sA1t, g, m, acc2);
    f32x4 h2[4];
    #pragma unroll
    for (int t = 0; t < 4; t++) h2[t] = acc2[t] + ab1[t];
    #pragma unroll
    for (int r = 0; r < 4; r++) {
      float s = h2[0][r] + h2[1][r] + h2[2][r] + h2[3][r];
      s += __shfl_xor(s, 1); s += __shfl_xor(s, 2); s += __shfl_xor(s, 4); s += __shfl_xor(s, 8);
      float mean = s * (1.f / 64.f);
      float q = 0.f;
      #pragma unroll
      for (int t = 0; t < 4; t++) { float dd = h2[t][r] - mean; q = fmaf(dd, dd, q); }
      q += __shfl_xor(q, 1); q += __shfl_xor(q, 2); q += __shfl_xor(q, 4); q += __shfl_xor(q, 8);
      float rs = rsqrtf(q * (1.f / 64.f) + 1e-5f);
      #pragma unroll
      for (int t = 0; t < 4; t++)
        h2[t][r] = fmaxf(fmaf((h2[t][r] - mean) * rs, agv[t], abv[t]), 0.f);
    }
    #pragma unroll
    for (int r = 0; r < 4; r++)
      #pragma unroll
      for (int t = 0; t < 4; t++)
        *(unsigned short*)(myAct + SWZ((4 * g + r) * 128 + 32 * t + 2 * m)) = f2b(h2[t][r]);
    lds_fence();

    // ---- GEMM3: alpha ----
    f32x4 acc3[4] = {};
    gemm16(myAct, sA2t, g, m, acc3);

    // ---- prefetch next group's gathers (hidden under phase E + next A) ----
    Gath Gn = load_gath(Mn, a_dstB, a_srcB, vBg, m);

    // ---- Phase E: exp, weighted values ----
    f32x4 nV[4], dV[4];
    #pragma unroll
    for (int r = 0; r < 4; r++) {
      float vf[4];
      unpack2(Gc.vv[r].x, vf[0], vf[1]); unpack2(Gc.vv[r].y, vf[2], vf[3]);
      bool val = Mc.md[r] >= 0;
      #pragma unroll
      for (int t = 0; t < 4; t++) {
        float e = __expf(acc3[t][r] + ab2[t]);
        e = val ? e : 0.f;
        nV[r][t] = e * (vf[t] + del[t][r]);
        dV[r][t] = e;
      }
    }

    // ---- segmented reduce: suffix partial + carry scan + tail flush ----
    // ALL shfls unconditional (convergent ops must not sit inside &&).
    {
      int d3 = Mc.md[3];
      bool s2 = (Mc.md[2] == d3);
      bool s1 = s2 && (Mc.md[1] == d3);
      bool s0 = s1 && (Mc.md[0] == d3);
      f32x4 PN = nV[3] + psel(s2, nV[2]) + psel(s1, nV[1]) + psel(s0, nV[0]);
      f32x4 PD = dV[3] + psel(s2, dV[2]) + psel(s1, dV[1]) + psel(s0, dV[0]);

      int dPrev3 = __shfl_up(d3, 16);
      int dNext0 = __shfl_down(Mc.md[0], 16);
      bool ok1 = (g > 0) && (Mc.md[0] == dPrev3);
      int okf = (ok1 && s0) ? 1 : 0;
      int okf1 = __shfl_up(okf, 16);   // unconditional
      int okf2 = __shfl_up(okf, 32);   // unconditional
      bool ok2 = ok1 && (okf1 != 0);
      bool ok3 = ok2 && (okf2 != 0);
      f32x4 sh16N = shup4<16>(PN), sh32N = shup4<32>(PN), sh48N = shup4<48>(PN);
      f32x4 sh16D = shup4<16>(PD), sh32D = shup4<32>(PD), sh48D = shup4<48>(PD);
      f32x4 CN = psel(ok1, sh16N) + psel(ok2, sh32N) + psel(ok3, sh48N);
      f32x4 CD = psel(ok1, sh16D) + psel(ok2, sh32D) + psel(ok3, sh48D);

      int dn[4] = { Mc.md[1], Mc.md[2], Mc.md[3], (g == 3) ? (int)0x80000000 : dNext0 };

      f32x4 aN = CN, aD = CD;
      #pragma unroll
      for (int r = 0; r < 4; r++) {
        aN += nV[r]; aD += dV[r];
        if (Mc.md[r] != dn[r]) {
          if (Mc.md[r] >= 0) {
            float* np = &numer[(size_t)Mc.md[r] * 64 + 4 * m];
            float* dp = &denom[(size_t)Mc.md[r] * 64 + 4 * m];
            #pragma unroll
            for (int t = 0; t < 4; t++) { atomicAdd(np + t, aN[t]); atomicAdd(dp + t, aD[t]); }
          }
          f32x4 z = {0.f, 0.f, 0.f, 0.f};
          aN = z; aD = z;
        }
      }
    }

    Mc = Mn; Gc = Gn;
  }
}

// ---------------- output linear (MFMA) ----------------
__global__ __launch_bounds__(256) void out_mfma_kernel(
    const float* __restrict__ numer, const float* __restrict__ denom,
    const float* __restrict__ W_out, const float* __restrict__ b_out,
    float* __restrict__ out, int N)
{
  __shared__ __align__(16) char sWoT[8192], sX[8192];
  __shared__ float sB[64];
  int tid = threadIdx.x;
  stage_wt(W_out, sWoT, tid);
  if (tid < 64) sB[tid] = b_out[tid];

  const int lane = tid & 63, wv = tid >> 6;
  const int g = lane >> 4, m = lane & 15;
  const int ew = wv << 4;
  const int srow = tid >> 2, sc0 = (tid & 3) << 4;
  const int ntile = (N + 63) >> 6;

  for (int tile = blockIdx.x; tile < ntile; tile += gridDim.x) {
    const int rbase = tile << 6;
    __syncthreads();
    {
      int gr = rbase + srow; if (gr >= N) gr = N - 1;
      const float4* nsrc = (const float4*)&numer[(size_t)gr * 64 + sc0];
      const float4* dsrc = (const float4*)&denom[(size_t)gr * 64 + sc0];
      #pragma unroll
      for (int q = 0; q < 4; q++) {
        float4 fn = nsrc[q], fd = dsrc[q];
        float m0 = fn.x / fmaxf(fd.x, 1e-16f);
        float m1 = fn.y / fmaxf(fd.y, 1e-16f);
        float m2 = fn.z / fmaxf(fd.z, 1e-16f);
        float m3 = fn.w / fmaxf(fd.w, 1e-16f);
        int byte = srow * 128 + sc0 * 2 + q * 8;
        *(unsigned int*)(sX + SWZ(byte))     = pack2(m0, m1);
        *(unsigned int*)(sX + SWZ(byte + 4)) = pack2(m2, m3);
      }
    }
    __syncthreads();
    f32x4 acc[4] = {};
    gemm16(sX + ew * 128, sWoT, g, m, acc);
    #pragma unroll
    for (int t = 0; t < 4; t++)
      #pragma unroll
      for (int r = 0; r < 4; r++) {
        int gr = rbase + ew + 4 * g + r;
        if (gr < N) out[(size_t)gr * 64 + t * 16 + m] = fmaxf(acc[t][r] + sB[t * 16 + m], 0.f);
      }
  }
}

extern "C" void kernel_launch(void* const* d_in, const int* in_sizes, int n_in,
                              void* d_out, int out_size, void* d_ws, size_t ws_size,
                              hipStream_t stream) {
  (void)n_in; (void)out_size; (void)ws_size;
  const float* x        = (const float*)d_in[0];
  const float* pos      = (const float*)d_in[1];
  const int*   ei       = (const int*)  d_in[2];
  const float* W_in     = (const float*)d_in[3];
  const float* b_in     = (const float*)d_in[4];
  const float* W_lin    = (const float*)d_in[5];
  const float* W_src    = (const float*)d_in[6];
  const float* W_dst    = (const float*)d_in[7];
  const float* pos_W1   = (const float*)d_in[8];
  const float* pos_b1   = (const float*)d_in[9];
  const float* pos_g    = (const float*)d_in[10];
  const float* pos_beta = (const float*)d_in[11];
  const float* pos_W2   = (const float*)d_in[12];
  const float* pos_b2   = (const float*)d_in[13];
  const float* att_W1   = (const float*)d_in[14];
  const float* att_b1   = (const float*)d_in[15];
  const float* att_g    = (const float*)d_in[16];
  const float* att_beta = (const float*)d_in[17];
  const float* att_W2   = (const float*)d_in[18];
  const float* att_b2   = (const float*)d_in[19];
  const float* W_out    = (const float*)d_in[20];
  const float* b_out    = (const float*)d_in[21];

  const int N    = in_sizes[0] / 64;
  const int E    = in_sizes[2] / 2;
  const int Etot = E + N;
  const int Epad = (Etot + 15) & ~15;
  const size_t N64 = (size_t)N * 64;

  float* numer = (float*)d_ws;
  float* denom = numer + N64;
  unsigned short* aSb = (unsigned short*)(denom + N64);
  unsigned short* aDb = aSb + N64;
  unsigned short* vBb = aDb + N64;
  float4* pd4 = (float4*)(vBb + N64);
  int* srcS     = (int*)(pd4 + Epad);
  int* dstS     = srcS + Epad;
  int* deg      = dstS + Epad;
  int* cursor   = deg + N;
  int* chunkSum = cursor + N;
  int* chunkPre = chunkSum + 256;

  const int nchunk = (N + 255) / 256;

  hipMemsetAsync(deg, 0, (size_t)N * sizeof(int), stream);
  hipMemsetAsync(numer, 0, 2 * N64 * sizeof(float), stream);
  if (Epad > Etot) {
    hipMemsetAsync(dstS + Etot, 0xFF, (size_t)(Epad - Etot) * sizeof(int), stream);
    hipMemsetAsync(srcS + Etot, 0, (size_t)(Epad - Etot) * sizeof(int), stream);
    hipMemsetAsync(pd4 + Etot, 0, (size_t)(Epad - Etot) * sizeof(float4), stream);
  }

  hist_kernel<<<1024, 256, 0, stream>>>(ei, deg, E, Etot);
  scanA_kernel<<<nchunk, 256, 0, stream>>>(deg, chunkSum, N);
  scanB_kernel<<<1, 256, 0, stream>>>(chunkSum, chunkPre, nchunk);
  scanC_kernel<<<nchunk, 256, 0, stream>>>(deg, chunkPre, cursor, N);
  scatter_kernel<<<1024, 256, 0, stream>>>(ei, cursor, pos, srcS, dstS, pd4, E, Etot);

  const int ntileN = (N + 63) / 64;
  const int nblkN  = ntileN < 768 ? ntileN : 768;
  node_mfma_kernel<<<nblkN, 256, 0, stream>>>(x, W_in, b_in, W_lin, W_src, W_dst,
                                              aSb, aDb, vBb, N);

  const int G   = Epad / 16;
  const int NB  = 768;
  const int gpw = (G + NB * 4 - 1) / (NB * 4);
  edge_kernel<<<NB, 256, 0, stream>>>(srcS, dstS, pd4, aSb, aDb, vBb,
      pos_W1, pos_b1, pos_g, pos_beta, pos_W2, pos_b2,
      att_W1, att_b1, att_g, att_beta, att_W2, att_b2,
      numer, denom, G, gpw);

  out_mfma_kernel<<<nblkN, 256, 0, stream>>>(numer, denom, W_out, b_out, (float*)d_out, N);
}